// Round 15
// baseline (190.834 us; speedup 1.0000x reference)
//
#include <hip/hip_runtime.h>
#include <hip/hip_bf16.h>

// SelfAttention: x[2,2048,1024] fp32; w_qkv[3072,1024]; w_out[1024,1024]; b_out[1024]
// Pipeline:
//  (0) cvt_all: x, w_qkv (q rows pre-scaled by 0.125*log2e), w_out -> bf16 ws
//  (1) gemm128<0,128>: qkv = x @ w_qkv^T (T1 XCD swizzle; 768 blocks = 3/CU)
//      R13b: v-epilogue now transposes via LDS (reuses staging buffer) ->
//      key-contiguous 16B stores. Old path: 8B stores 4KB apart (64 lines
//      per wave-inst, ~8x write amplification on vt).
//  (2) attn_kernel R11 (verified 54.5 us): QBLK=128, 8 waves, role-split
//      staging, dbuf single-barrier. Per-wave compute VERBATIM R5 — FROZEN.
//  (3) gemm128<1,64>: out = attn @ w_out^T + b_out (512 blocks = 2/CU)
// GEMM: BM=128, BK=64, global_load_lds w=16, XOR-swizzle (2-way banks, free).
// 32x32 C/D layout: col=lane&31 (B's n), row=(reg&3)+8*(reg>>2)+4*(lane>>5).
// 32x32 A/B frag: lane&31 = m/n, k = (lane>>5)*8 + j (8 contiguous bf16 = 16 B).
// JOURNAL:
//  - R2 WIN dbuf single-barrier attn: 61.1. R5 WIN V-hoist+permlane: 58.3.
//  - R7/R8 FAIL: softmax->permlane region schedule-sensitive. FROZEN.
//  - R10 WIN: T1 XCD swizzle: 187.4 -> 181.4.
//  - R11 attn QBLK=128: attn -> 55.0 WIN. R12: proj BN=128 (1 blk/CU)
//    regressed; R13 reverted proj -> 182.5 (attn 54.5).
//  - R13b: QKV v-epilogue LDS-transpose -> coalesced stores (epilogue audit
//    re-verified: coverage/sync/LDS-size all check out).
//  - R14 (this): R13b bench was an infra timeout — resubmitting unchanged.
//    Predict total ~170-177. If <3us move: v-scatter wasn't the cost.

#define SEQ   2048
#define BATCH 2
#define CDIM  1024
#define NH    16
#define HD    64
#define NTOK  (BATCH*SEQ)
#define QSCALE 0.18033688011f   // 0.125 * log2(e)

typedef __attribute__((ext_vector_type(8)))  short s16x8;
typedef __attribute__((ext_vector_type(4)))  float f32x4;
typedef __attribute__((ext_vector_type(16))) float f32x16;
typedef __attribute__((ext_vector_type(4)))  unsigned u32x4;
typedef __attribute__((ext_vector_type(2)))  __bf16 bf16x2;

__device__ __forceinline__ short f2bf(float x) {
  unsigned u = __builtin_bit_cast(unsigned, x);
  u = (u + 0x7fffu + ((u >> 16) & 1u)) >> 16;
  return (short)u;
}

// pack two fp32 -> bf16x2 in one u32 (low=a, high=b)
__device__ __forceinline__ unsigned f2bf2(float a, float b) {
#if __has_builtin(__builtin_amdgcn_cvt_pk_bf16_f32)
  bf16x2 v = __builtin_amdgcn_cvt_pk_bf16_f32(a, b);
  return __builtin_bit_cast(unsigned, v);
#else
  unsigned ua = __builtin_bit_cast(unsigned, a) + 0x8000u;
  unsigned ub = __builtin_bit_cast(unsigned, b) + 0x8000u;
  return (ub & 0xffff0000u) | (ua >> 16);
#endif
}

__device__ __forceinline__ float exp2_fast(float x) {
  return __builtin_amdgcn_exp2f(x);   // v_exp_f32
}

__device__ __forceinline__ void gl2lds16(const short* g, short* l) {
  __builtin_amdgcn_global_load_lds(
      (const __attribute__((address_space(1))) void*)g,
      (__attribute__((address_space(3))) void*)l, 16, 0, 0);
}

// ---------------------------------------------------------------------------
// Fused fp32 -> bf16 converts (x | w_qkv(q-scaled) | w_out), 2048 elem/block.
// ---------------------------------------------------------------------------
__global__ __launch_bounds__(256) void cvt_all(
    const float* __restrict__ x, const float* __restrict__ wqkv,
    const float* __restrict__ wout, short* __restrict__ x_bf,
    short* __restrict__ wqkv_bf, short* __restrict__ wout_bf)
{
  int blk = blockIdx.x;
  const float* src; short* dst; int base; float scale = 1.0f;
  if (blk < 2048)      { src = x;    dst = x_bf;    base = blk; }
  else if (blk < 3584) { src = wqkv; dst = wqkv_bf; base = blk - 2048;
                         if (base < 512) scale = QSCALE; }  // q rows
  else                 { src = wout; dst = wout_bf; base = blk - 3584; }
  size_t i = ((size_t)base * 256 + threadIdx.x) * 8;
  float4 v0 = *(const float4*)(src + i);
  float4 v1 = *(const float4*)(src + i + 4);
  s16x8 p;
  p[0]=f2bf(v0.x*scale); p[1]=f2bf(v0.y*scale); p[2]=f2bf(v0.z*scale); p[3]=f2bf(v0.w*scale);
  p[4]=f2bf(v1.x*scale); p[5]=f2bf(v1.y*scale); p[6]=f2bf(v1.z*scale); p[7]=f2bf(v1.w*scale);
  *(s16x8*)(dst + i) = p;
}

// ---------------------------------------------------------------------------
// GEMM: C[M,N] = A[M,K] @ B[N,K]^T, bf16. BM=128, BK=64, 4 waves, 256 thr.
// BN=128: wave 64x64 acc[4][4]; BN=64: wave 64x32 acc[4][2].
// LDS [rows][64] shorts; 16B chunk at (row,pos) holds global chunk
// pos ^ (row&7); frag reads hit bank-group quad^(lrow&7) -> 2-way (free).
// T1 XCD-chunked swizzle (R10 WIN): id%8 = XCD -> contiguous tile chunk.
// MODE 0: QKV epilogue. q,k -> qk bf16 pitch 2048 (32B-segment stores).
//   v -> vt transposed: R13b LDS-transpose (T[d][key] pitch 136, two
//   64-d passes) -> 4x coalesced 16B key-contiguous stores per thread.
// MODE 1: fp32 + bias epilogue.
// ---------------------------------------------------------------------------
template<int MODE, int BN>
__global__ __launch_bounds__(256) void gemm128(
    const short* __restrict__ A, const short* __restrict__ B,
    const float* __restrict__ bias, void* __restrict__ Cp,
    short* __restrict__ vt, int M, int N, int K)
{
  constexpr int TN = BN / 32;     // acc tiles per wave in N (4 or 2)
  constexpr int NB = BN / 32;     // B-staging gl2lds per thread (4 or 2)

  __shared__ __align__(16) short smem[128 * 64 + BN * 64];
  short* As = smem;
  short* Bs = smem + 128 * 64;

  const int t    = threadIdx.x;
  const int w    = t >> 6, lane = t & 63;

  // T1 XCD-chunked swizzle: physical id%8 = XCD -> contiguous tile chunk.
  const int nwgx = gridDim.x;
  const int id   = blockIdx.y * nwgx + blockIdx.x;
  const int cpx  = (nwgx * gridDim.y) >> 3;
  const int swz  = (id & 7) * cpx + (id >> 3);
  const int bm   = (swz / nwgx) * 128, bn = (swz % nwgx) * BN;

  const int wm   = (w >> 1) * 64, wn = (w & 1) * (BN / 2);
  const int lrow = lane & 15, quad = lane >> 4;

  int goffA[4], goffB[NB];
#pragma unroll
  for (int i = 0; i < 4; i++) {
    int L   = (w * 4 + i) * 64 + lane;     // 16B-chunk index in 128x64 tile
    int row = L >> 3, pos = L & 7;
    int src = pos ^ (row & 7);
    goffA[i] = (bm + row) * K + src * 8;
  }
#pragma unroll
  for (int i = 0; i < NB; i++) {
    int L   = (w * NB + i) * 64 + lane;
    int row = L >> 3, pos = L & 7;
    int src = pos ^ (row & 7);
    goffB[i] = (bn + row) * K + src * 8;
  }
  const int fk0 = (quad ^ (lrow & 7)) * 8;
  const int fk1 = fk0 ^ 32;

  f32x4 acc[4][TN];
#pragma unroll
  for (int i = 0; i < 4; i++)
#pragma unroll
    for (int j = 0; j < TN; j++) acc[i][j] = (f32x4){0.f, 0.f, 0.f, 0.f};

  for (int k0 = 0; k0 < K; k0 += 64) {
    __syncthreads();
#pragma unroll
    for (int i = 0; i < 4; i++)
      gl2lds16(A + goffA[i] + k0, &As[(w * 4 + i) * 512]);
#pragma unroll
    for (int i = 0; i < NB; i++)
      gl2lds16(B + goffB[i] + k0, &Bs[(w * NB + i) * 512]);
    __syncthreads();

    s16x8 a[4][2], b[TN][2];
#pragma unroll
    for (int tm = 0; tm < 4; tm++) {
      a[tm][0] = *(const s16x8*)&As[(wm + tm * 16 + lrow) * 64 + fk0];
      a[tm][1] = *(const s16x8*)&As[(wm + tm * 16 + lrow) * 64 + fk1];
    }
#pragma unroll
    for (int tn = 0; tn < TN; tn++) {
      b[tn][0] = *(const s16x8*)&Bs[(wn + tn * 16 + lrow) * 64 + fk0];
      b[tn][1] = *(const s16x8*)&Bs[(wn + tn * 16 + lrow) * 64 + fk1];
    }
#pragma unroll
    for (int hh = 0; hh < 2; hh++)
#pragma unroll
      for (int tm = 0; tm < 4; tm++)
#pragma unroll
        for (int tn = 0; tn < TN; tn++)
          acc[tm][tn] = __builtin_amdgcn_mfma_f32_16x16x32_bf16(
              a[tm][hh], b[tn][hh], acc[tm][tn], 0, 0, 0);
  }

  if (MODE == 1) {
#pragma unroll
    for (int tm = 0; tm < 4; tm++)
#pragma unroll
      for (int tn = 0; tn < TN; tn++)
#pragma unroll
        for (int i = 0; i < 4; i++) {
          int row = bm + wm + tm * 16 + quad * 4 + i;
          int col = bn + wn + tn * 16 + lrow;
          ((float*)Cp)[(size_t)row * N + col] = acc[tm][tn][i] + bias[col];
        }
  } else if (bn < 2 * CDIM) {
#pragma unroll
    for (int tm = 0; tm < 4; tm++)
#pragma unroll
      for (int tn = 0; tn < TN; tn++)
#pragma unroll
        for (int i = 0; i < 4; i++) {
          int row = bm + wm + tm * 16 + quad * 4 + i;
          int col = bn + wn + tn * 16 + lrow;
          ((short*)Cp)[(size_t)row * 2048 + col] = f2bf(acc[tm][tn][i]);
        }
  } else {
    // v epilogue (R13b): transpose via LDS -> key-contiguous 16B stores.
    // Two passes over d-halves; T[d 0..63][key 0..127] pitch 136 shorts
    // (272 B: 16B-aligned rows). T reuses smem (needs 8704 shorts <= 16384).
    short* T = smem;
    const int bmkey = bm & (SEQ - 1);
    const int bb    = bm >> 11;
#pragma unroll
    for (int dhalf = 0; dhalf < 2; dhalf++) {
      __syncthreads();                       // staging / prior pass dead
      if ((w & 1) == dhalf) {                // waves owning this d-half
#pragma unroll
        for (int tm = 0; tm < 4; tm++)
#pragma unroll
          for (int tn = 0; tn < TN; tn++)
#pragma unroll
            for (int i = 0; i < 4; i++) {
              int dL   = tn * 16 + lrow;                 // 0..63 in half
              int keyL = wm + tm * 16 + quad * 4 + i;    // 0..127
              T[dL * 136 + keyL] = f2bf(acc[tm][tn][i]);
            }
      }
      __syncthreads();
      // 64 d-rows x 128 keys = 1024 16B chunks; 4 per thread, coalesced.
#pragma unroll
      for (int j = 0; j < 4; j++) {
        int c2  = t * 4 + j;
        int dL  = c2 >> 4, kc2 = c2 & 15;
        int vcol = bn - 2 * CDIM + dhalf * 64 + dL;
        int hh2  = vcol >> 6, dd = vcol & 63;
        size_t off = (((size_t)(bb * NH + hh2) * HD + dd) << 11)
                     + bmkey + kc2 * 8;
        *(s16x8*)(vt + off) = *(const s16x8*)&T[dL * 136 + kc2 * 8];
      }
    }
  }
}

// ---------------------------------------------------------------------------
// Flash attention R11 (verified 54.5 us): QBLK=128, 8 waves = 4 wq x 2 wk.
// Per-wave compute is VERBATIM R5 (FROZEN: QK->softmax->cvt_pk->permlane->PV
// — R7/R8 perturbations corrupted output). Staging role-split: waves 0-3
// stage K, waves 4-7 stage V (r7 conflict-free pattern over t&255,
// 2x16B/thread/chunk). dbuf, one barrier per 64-key chunk; register
// prefetch 2 chunks ahead. Epilogue: cross-wk O/l reduce via LDS
// (Ored [4][32][64] = 32 KB, Lred [128] — fits 36 KB smem).
// ---------------------------------------------------------------------------
#define KPITCH 72
#define ABUFSZ (2 * 64 * KPITCH)   // Ks+Vs per buffer = 9216 shorts (18 KB)

__global__ __launch_bounds__(512, 4) void attn_kernel(
    const short* __restrict__ qk, const short* __restrict__ vt,
    short* __restrict__ attn_out)
{
  __shared__ __align__(16) short smem[2 * ABUFSZ];   // 36 KB

  const int t   = threadIdx.x;
  const int w   = t >> 6, lane = t & 63;
  const int l31 = lane & 31, h = lane >> 5;
  const int wq  = w & 3, wk = w >> 2;
  const int bh  = blockIdx.x;
  const int b   = bh >> 4, hd = bh & (NH - 1);
  const int q0  = blockIdx.y * 128;

  const short* base  = qk + (size_t)(b * SEQ) * 2048 + hd * HD;
  const short* vbase = vt + ((size_t)(b * NH + hd) * HD) * SEQ;

  // Q B-frags in registers (pre-scaled): n=q, k=d=c*16+h*8+j
  s16x8 qf[4];
  {
    const short* qp = base + (size_t)(q0 + wq * 32 + l31) * 2048;
#pragma unroll
    for (int c = 0; c < 4; c++) qf[c] = *(const s16x8*)(qp + c * 16 + h * 8);
  }

  f32x16 o0 = {}, o1 = {};
  float lsum = 0.f;

  // role-split staging: waves 0-3 stage K, waves 4-7 stage V.
  // r7 conflict-free pattern over t&255: sr 0..63, sc in {0,16,32,48}.
  const int tt = t & 255;
  const int sr = tt >> 2, sc = (tt & 3) * 16;
  const bool stageK = (w < 4);

  s16x8 p0, p1;
  // load chunk 0
  {
    const short* gp = stageK ? (base + (size_t)sr * 2048 + CDIM + sc)
                             : (vbase + (size_t)sr * SEQ + sc);
    p0 = *(const s16x8*)gp; p1 = *(const s16x8*)(gp + 8);
  }
  // stage chunk 0 into buf0
  {
    short* dst = stageK ? smem : (smem + 64 * KPITCH);
    *(s16x8*)&dst[sr * KPITCH + sc]     = p0;
    *(s16x8*)&dst[sr * KPITCH + sc + 8] = p1;
  }
  __syncthreads();
  // load chunk 1
  {
    const short* gp = stageK ? (base + (size_t)(64 + sr) * 2048 + CDIM + sc)
                             : (vbase + (size_t)sr * SEQ + 64 + sc);
    p0 = *(const s16x8*)gp; p1 = *(const s16x8*)(gp + 8);
  }

  int cur = 0;
  for (int i = 0; i < SEQ / 64; i++) {
    short* Ksc = smem + cur * ABUFSZ;
    short* Vsc = Ksc + 64 * KPITCH;

    // stage chunk i+1 (in regs) into next buffer — overlaps compute below
    if (i <= SEQ / 64 - 2) {
      short* dst = (smem + (cur ^ 1) * ABUFSZ) + (stageK ? 0 : 64 * KPITCH);
      *(s16x8*)&dst[sr * KPITCH + sc]     = p0;
      *(s16x8*)&dst[sr * KPITCH + sc + 8] = p1;
    }

    // issue global loads for chunk i+2 (in flight across compute + barrier)
    if (i <= SEQ / 64 - 3) {
      int nn = (i + 2) * 64;
      const short* gp = stageK ? (base + (size_t)(nn + sr) * 2048 + CDIM + sc)
                               : (vbase + (size_t)sr * SEQ + nn + sc);
      p0 = *(const s16x8*)gp; p1 = *(const s16x8*)(gp + 8);
    }

    // ---- FROZEN per-wave compute (verbatim R5) ----
    const short* kbase = &Ksc[(wk * 32 + l31) * KPITCH + h * 8];
    s16x8 kf0 = *(const s16x8*)(kbase + 0);
    s16x8 kf1 = *(const s16x8*)(kbase + 16);
    s16x8 kf2 = *(const s16x8*)(kbase + 32);
    s16x8 kf3 = *(const s16x8*)(kbase + 48);
    s16x8 va0 = *(const s16x8*)&Vsc[l31 * KPITCH        + wk * 32 + h * 8];
    s16x8 va1 = *(const s16x8*)&Vsc[(32 + l31) * KPITCH + wk * 32 + h * 8];
    s16x8 vb0 = *(const s16x8*)&Vsc[l31 * KPITCH        + wk * 32 + 16 + h * 8];
    s16x8 vb1 = *(const s16x8*)&Vsc[(32 + l31) * KPITCH + wk * 32 + 16 + h * 8];

    // S^T[key][q]: A = K rows (wk half), B = Q regs. Two parallel chains.
    f32x16 sa = {}, sb = {};
    sa = __builtin_amdgcn_mfma_f32_32x32x16_bf16(kf0, qf[0], sa, 0, 0, 0);
    sb = __builtin_amdgcn_mfma_f32_32x32x16_bf16(kf2, qf[2], sb, 0, 0, 0);
    sa = __builtin_amdgcn_mfma_f32_32x32x16_bf16(kf1, qf[1], sa, 0, 0, 0);
    sb = __builtin_amdgcn_mfma_f32_32x32x16_bf16(kf3, qf[3], sb, 0, 0, 0);

    // softmax + pack: reg r -> key (r&3)+8*(r>>2)+4h (local to wave's half)
    uint2 pg[4];
#pragma unroll
    for (int g = 0; g < 4; g++) {
      float p0f = exp2_fast(sa[4 * g + 0] + sb[4 * g + 0]);
      float p1f = exp2_fast(sa[4 * g + 1] + sb[4 * g + 1]);
      float p2f = exp2_fast(sa[4 * g + 2] + sb[4 * g + 2]);
      float p3f = exp2_fast(sa[4 * g + 3] + sb[4 * g + 3]);
      lsum += (p0f + p1f) + (p2f + p3f);
      pg[g].x = f2bf2(p0f, p1f);
      pg[g].y = f2bf2(p2f, p3f);
    }

    // C->A via permlane32_swap (vdst=a=low-keys, vsrc=b=high-keys):
    //   new_a -> A-frag word0/1, new_b -> word2/3
    s16x8 pf[2];
#pragma unroll
    for (int kc2 = 0; kc2 < 2; kc2++) {
      unsigned a0 = pg[2 * kc2].x,     a1 = pg[2 * kc2].y;
      unsigned b0 = pg[2 * kc2 + 1].x, b1 = pg[2 * kc2 + 1].y;
      asm("v_permlane32_swap_b32 %0, %1" : "+v"(a0), "+v"(b0));
      asm("v_permlane32_swap_b32 %0, %1" : "+v"(a1), "+v"(b1));
      u32x4 f = {a0, a1, b0, b1};
      pf[kc2] = __builtin_bit_cast(s16x8, f);
    }

    // PV: O[q][d] += P * V over wave's 32 keys; B-frags preloaded above
    o0 = __builtin_amdgcn_mfma_f32_32x32x16_bf16(pf[0], va0, o0, 0, 0, 0);
    o1 = __builtin_amdgcn_mfma_f32_32x32x16_bf16(pf[0], va1, o1, 0, 0, 0);
    o0 = __builtin_amdgcn_mfma_f32_32x32x16_bf16(pf[1], vb0, o0, 0, 0, 0);
    o1 = __builtin_amdgcn_mfma_f32_32x32x16_bf16(pf[1], vb1, o1, 0, 0, 0);
    // ---- end FROZEN ----

    __syncthreads();                 // one barrier per chunk
    cur ^= 1;
  }

  // ---- epilogue: cross-wk reduction of O and l, normalize, store ----
  lsum += __shfl_xor(lsum, 32);          // combine h halves (disjoint keys)

  float* Ored = (float*)smem;            // [4 wq][32 q][64 d] = 32 KB
  float* Lred = (float*)smem + 8192;     // [128]

  if (wk == 0) {
#pragma unroll
    for (int r = 0; r < 16; r++) {
      int ql = (r & 3) + 8 * (r >> 2) + 4 * h;
      Ored[(wq * 32 + ql) * 64 + l31]      = o0[r];
      Ored[(wq * 32 + ql) * 64 + 32 + l31] = o1[r];
    }
    if (lane < 32) Lred[wq * 32 + l31] = lsum;
  }
  __syncthreads();
  if (wk == 1 && lane < 32) Lred[wq * 32 + l31] += lsum;
  __syncthreads();
  if (wk == 1) {
#pragma unroll
    for (int r = 0; r < 16; r++) {
      int ql = (r & 3) + 8 * (r >> 2) + 4 * h;
      float linv = 1.0f / Lred[wq * 32 + ql];
      int qg = q0 + wq * 32 + ql;
      size_t rowb = (size_t)(b * SEQ + qg) * CDIM + hd * HD;
      float v0 = (o0[r] + Ored[(wq * 32 + ql) * 64 + l31]) * linv;
      float v1 = (o1[r] + Ored[(wq * 32 + ql) * 64 + 32 + l31]) * linv;
      attn_out[rowb + l31]      = f2bf(v0);
      attn_out[rowb + 32 + l31] = f2bf(v1);
    }
  }
}

// ---------------------------------------------------------------------------
extern "C" void kernel_launch(void* const* d_in, const int* in_sizes, int n_in,
                              void* d_out, int out_size, void* d_ws, size_t ws_size,
                              hipStream_t stream)
{
  const float* x     = (const float*)d_in[0];
  const float* w_qkv = (const float*)d_in[1];
  const float* w_out = (const float*)d_in[2];
  const float* b_out = (const float*)d_in[3];

  short* qk_ws   = (short*)d_ws;                         // 4096*2048 = 16 MB
  short* vt_ws   = qk_ws  + (size_t)NTOK * 2048;         // 4096*1024 =  8 MB
  short* x_bf    = vt_ws  + (size_t)NTOK * CDIM;         // 4096*1024 =  8 MB
  short* attn_ws = x_bf;                                 // alias (x_bf dead)
  short* wqkv_bf = x_bf   + (size_t)NTOK * CDIM;         // 3072*1024 =  6 MB
  short* wout_bf = wqkv_bf + (size_t)3 * CDIM * CDIM;    // 1024*1024 =  2 MB

  dim3 blk(256);

  cvt_all<<<dim3(4096), blk, 0, stream>>>(x, w_qkv, w_out, x_bf, wqkv_bf, wout_bf);

  gemm128<0, 128><<<dim3(3 * CDIM / 128, NTOK / 128), blk, 0, stream>>>(
      x_bf, wqkv_bf, nullptr, qk_ws, vt_ws, NTOK, 3 * CDIM, CDIM);

  attn_kernel<<<dim3(BATCH * NH, SEQ / 128), dim3(512), 0, stream>>>(
      qk_ws, vt_ws, attn_ws);

  gemm128<1, 64><<<dim3(CDIM / 64, NTOK / 128), blk, 0, stream>>>(
      attn_ws, wout_bf, b_out, d_out, nullptr, NTOK, CDIM, CDIM);
}

// Round 16
// 177.159 us; speedup vs baseline: 1.0772x; 1.0772x over previous
//
#include <hip/hip_runtime.h>
#include <hip/hip_bf16.h>

// SelfAttention: x[2,2048,1024] fp32; w_qkv[3072,1024]; w_out[1024,1024]; b_out[1024]
// Pipeline:
//  (0) cvt_all: x, w_qkv (q rows pre-scaled by 0.125*log2e), w_out -> bf16 ws
//  (1) gemm128<0,128>: qkv = x @ w_qkv^T (T1 XCD swizzle; 768 blocks = 3/CU)
//  (2) attn_kernel R11 (verified 54.5 us): QBLK=128, 8 waves, role-split
//      staging, dbuf single-barrier. Per-wave compute VERBATIM R5 — FROZEN.
//  (3) gemm128<1,64>: out = attn @ w_out^T + b_out (512 blocks = 2/CU)
// GEMM: BM=128, BK=64, global_load_lds w=16, XOR-swizzle (2-way banks, free).
// 32x32 C/D layout: col=lane&31 (B's n), row=(reg&3)+8*(reg>>2)+4*(lane>>5).
// 32x32 A/B frag: lane&31 = m/n, k = (lane>>5)*8 + j (8 contiguous bf16 = 16 B).
// JOURNAL:
//  - R2 WIN dbuf single-barrier attn: 61.1. R5 WIN V-hoist+permlane: 58.3.
//  - R7/R8 FAIL: softmax->permlane region schedule-sensitive. FROZEN.
//  - R10 WIN: T1 XCD swizzle: 187.4 -> 181.4.
//  - R11 attn QBLK=128: attn -> 55.0/54.5 WIN. R12: proj BN=128 (1 blk/CU)
//    regressed; R13: proj BN=64 -> total 182.5 (~R11's 181.4 within noise).
//  - R15 FAIL: v-epilogue LDS-transpose regressed 182.5 -> 190.8 (+8.3,
//    outside noise). Scattered uint2 v-stores were NOT a bottleneck (L2
//    write-combining absorbs them); the LDS transpose added 64 scalar
//    ds_write_b16/thread + 4 barriers of real cost. Store-path changes
//    need WRITE_SIZE evidence first. REVERTED.
//  - R15 profile: no GEMM dispatch > 54.9 us — no dominant dispatch left.
//  - R16 (this): byte-identical R13 restore (best steady-state config).

#define SEQ   2048
#define BATCH 2
#define CDIM  1024
#define NH    16
#define HD    64
#define NTOK  (BATCH*SEQ)
#define QSCALE 0.18033688011f   // 0.125 * log2(e)

typedef __attribute__((ext_vector_type(8)))  short s16x8;
typedef __attribute__((ext_vector_type(4)))  float f32x4;
typedef __attribute__((ext_vector_type(16))) float f32x16;
typedef __attribute__((ext_vector_type(4)))  unsigned u32x4;
typedef __attribute__((ext_vector_type(2)))  __bf16 bf16x2;

__device__ __forceinline__ short f2bf(float x) {
  unsigned u = __builtin_bit_cast(unsigned, x);
  u = (u + 0x7fffu + ((u >> 16) & 1u)) >> 16;
  return (short)u;
}

// pack two fp32 -> bf16x2 in one u32 (low=a, high=b)
__device__ __forceinline__ unsigned f2bf2(float a, float b) {
#if __has_builtin(__builtin_amdgcn_cvt_pk_bf16_f32)
  bf16x2 v = __builtin_amdgcn_cvt_pk_bf16_f32(a, b);
  return __builtin_bit_cast(unsigned, v);
#else
  unsigned ua = __builtin_bit_cast(unsigned, a) + 0x8000u;
  unsigned ub = __builtin_bit_cast(unsigned, b) + 0x8000u;
  return (ub & 0xffff0000u) | (ua >> 16);
#endif
}

__device__ __forceinline__ float exp2_fast(float x) {
  return __builtin_amdgcn_exp2f(x);   // v_exp_f32
}

__device__ __forceinline__ void gl2lds16(const short* g, short* l) {
  __builtin_amdgcn_global_load_lds(
      (const __attribute__((address_space(1))) void*)g,
      (__attribute__((address_space(3))) void*)l, 16, 0, 0);
}

// ---------------------------------------------------------------------------
// Fused fp32 -> bf16 converts (x | w_qkv(q-scaled) | w_out), 2048 elem/block.
// ---------------------------------------------------------------------------
__global__ __launch_bounds__(256) void cvt_all(
    const float* __restrict__ x, const float* __restrict__ wqkv,
    const float* __restrict__ wout, short* __restrict__ x_bf,
    short* __restrict__ wqkv_bf, short* __restrict__ wout_bf)
{
  int blk = blockIdx.x;
  const float* src; short* dst; int base; float scale = 1.0f;
  if (blk < 2048)      { src = x;    dst = x_bf;    base = blk; }
  else if (blk < 3584) { src = wqkv; dst = wqkv_bf; base = blk - 2048;
                         if (base < 512) scale = QSCALE; }  // q rows
  else                 { src = wout; dst = wout_bf; base = blk - 3584; }
  size_t i = ((size_t)base * 256 + threadIdx.x) * 8;
  float4 v0 = *(const float4*)(src + i);
  float4 v1 = *(const float4*)(src + i + 4);
  s16x8 p;
  p[0]=f2bf(v0.x*scale); p[1]=f2bf(v0.y*scale); p[2]=f2bf(v0.z*scale); p[3]=f2bf(v0.w*scale);
  p[4]=f2bf(v1.x*scale); p[5]=f2bf(v1.y*scale); p[6]=f2bf(v1.z*scale); p[7]=f2bf(v1.w*scale);
  *(s16x8*)(dst + i) = p;
}

// ---------------------------------------------------------------------------
// GEMM: C[M,N] = A[M,K] @ B[N,K]^T, bf16. BM=128, BK=64, 4 waves, 256 thr.
// BN=128: wave 64x64 acc[4][4]; BN=64: wave 64x32 acc[4][2].
// LDS [rows][64] shorts; 16B chunk at (row,pos) holds global chunk
// pos ^ (row&7); frag reads hit bank-group quad^(lrow&7) -> 2-way (free).
// T1 XCD-chunked swizzle (R10 WIN): id%8 = XCD -> contiguous tile chunk.
// Requires nwg%8==0: QKV 768 ok, proj 512 ok.
// MODE 0: QKV epilogue (q,k -> qk bf16 pitch 2048; v -> vt transposed).
// MODE 1: fp32 + bias epilogue.
// ---------------------------------------------------------------------------
template<int MODE, int BN>
__global__ __launch_bounds__(256) void gemm128(
    const short* __restrict__ A, const short* __restrict__ B,
    const float* __restrict__ bias, void* __restrict__ Cp,
    short* __restrict__ vt, int M, int N, int K)
{
  constexpr int TN = BN / 32;     // acc tiles per wave in N (4 or 2)
  constexpr int NB = BN / 32;     // B-staging gl2lds per thread (4 or 2)

  __shared__ __align__(16) short As[128 * 64];
  __shared__ __align__(16) short Bs[BN * 64];

  const int t    = threadIdx.x;
  const int w    = t >> 6, lane = t & 63;

  // T1 XCD-chunked swizzle: physical id%8 = XCD -> contiguous tile chunk.
  const int nwgx = gridDim.x;
  const int id   = blockIdx.y * nwgx + blockIdx.x;
  const int cpx  = (nwgx * gridDim.y) >> 3;
  const int swz  = (id & 7) * cpx + (id >> 3);
  const int bm   = (swz / nwgx) * 128, bn = (swz % nwgx) * BN;

  const int wm   = (w >> 1) * 64, wn = (w & 1) * (BN / 2);
  const int lrow = lane & 15, quad = lane >> 4;

  int goffA[4], goffB[NB];
#pragma unroll
  for (int i = 0; i < 4; i++) {
    int L   = (w * 4 + i) * 64 + lane;     // 16B-chunk index in 128x64 tile
    int row = L >> 3, pos = L & 7;
    int src = pos ^ (row & 7);
    goffA[i] = (bm + row) * K + src * 8;
  }
#pragma unroll
  for (int i = 0; i < NB; i++) {
    int L   = (w * NB + i) * 64 + lane;
    int row = L >> 3, pos = L & 7;
    int src = pos ^ (row & 7);
    goffB[i] = (bn + row) * K + src * 8;
  }
  const int fk0 = (quad ^ (lrow & 7)) * 8;
  const int fk1 = fk0 ^ 32;

  f32x4 acc[4][TN];
#pragma unroll
  for (int i = 0; i < 4; i++)
#pragma unroll
    for (int j = 0; j < TN; j++) acc[i][j] = (f32x4){0.f, 0.f, 0.f, 0.f};

  for (int k0 = 0; k0 < K; k0 += 64) {
    __syncthreads();
#pragma unroll
    for (int i = 0; i < 4; i++)
      gl2lds16(A + goffA[i] + k0, &As[(w * 4 + i) * 512]);
#pragma unroll
    for (int i = 0; i < NB; i++)
      gl2lds16(B + goffB[i] + k0, &Bs[(w * NB + i) * 512]);
    __syncthreads();

    s16x8 a[4][2], b[TN][2];
#pragma unroll
    for (int tm = 0; tm < 4; tm++) {
      a[tm][0] = *(const s16x8*)&As[(wm + tm * 16 + lrow) * 64 + fk0];
      a[tm][1] = *(const s16x8*)&As[(wm + tm * 16 + lrow) * 64 + fk1];
    }
#pragma unroll
    for (int tn = 0; tn < TN; tn++) {
      b[tn][0] = *(const s16x8*)&Bs[(wn + tn * 16 + lrow) * 64 + fk0];
      b[tn][1] = *(const s16x8*)&Bs[(wn + tn * 16 + lrow) * 64 + fk1];
    }
#pragma unroll
    for (int hh = 0; hh < 2; hh++)
#pragma unroll
      for (int tm = 0; tm < 4; tm++)
#pragma unroll
        for (int tn = 0; tn < TN; tn++)
          acc[tm][tn] = __builtin_amdgcn_mfma_f32_16x16x32_bf16(
              a[tm][hh], b[tn][hh], acc[tm][tn], 0, 0, 0);
  }

  if (MODE == 1) {
#pragma unroll
    for (int tm = 0; tm < 4; tm++)
#pragma unroll
      for (int tn = 0; tn < TN; tn++)
#pragma unroll
        for (int i = 0; i < 4; i++) {
          int row = bm + wm + tm * 16 + quad * 4 + i;
          int col = bn + wn + tn * 16 + lrow;
          ((float*)Cp)[(size_t)row * N + col] = acc[tm][tn][i] + bias[col];
        }
  } else if (bn < 2 * CDIM) {
#pragma unroll
    for (int tm = 0; tm < 4; tm++)
#pragma unroll
      for (int tn = 0; tn < TN; tn++)
#pragma unroll
        for (int i = 0; i < 4; i++) {
          int row = bm + wm + tm * 16 + quad * 4 + i;
          int col = bn + wn + tn * 16 + lrow;
          ((short*)Cp)[(size_t)row * 2048 + col] = f2bf(acc[tm][tn][i]);
        }
  } else {
#pragma unroll
    for (int tm = 0; tm < 4; tm++)
#pragma unroll
      for (int tn = 0; tn < TN; tn++) {
        int vcol = bn - 2 * CDIM + wn + tn * 16 + lrow;
        int h    = vcol >> 6, d = vcol & 63;
        int r0   = bm + wm + tm * 16 + quad * 4;
        int bb   = r0 >> 11, key = r0 & (SEQ - 1);
        size_t off = (((size_t)(bb * NH + h) * HD + d) << 11) + key;
        uint2 pk;
        pk.x = f2bf2(acc[tm][tn][0], acc[tm][tn][1]);
        pk.y = f2bf2(acc[tm][tn][2], acc[tm][tn][3]);
        *(uint2*)(vt + off) = pk;
      }
  }
}

// ---------------------------------------------------------------------------
// Flash attention R11 (verified 54.5 us): QBLK=128, 8 waves = 4 wq x 2 wk.
// Per-wave compute is VERBATIM R5 (FROZEN: QK->softmax->cvt_pk->permlane->PV
// — R7/R8 perturbations corrupted output). Staging role-split: waves 0-3
// stage K, waves 4-7 stage V (r7 conflict-free pattern over t&255,
// 2x16B/thread/chunk). dbuf, one barrier per 64-key chunk; register
// prefetch 2 chunks ahead. Epilogue: cross-wk O/l reduce via LDS
// (Ored [4][32][64] = 32 KB, Lred [128] — fits 36 KB smem).
// ---------------------------------------------------------------------------
#define KPITCH 72
#define ABUFSZ (2 * 64 * KPITCH)   // Ks+Vs per buffer = 9216 shorts (18 KB)

__global__ __launch_bounds__(512, 4) void attn_kernel(
    const short* __restrict__ qk, const short* __restrict__ vt,
    short* __restrict__ attn_out)
{
  __shared__ __align__(16) short smem[2 * ABUFSZ];   // 36 KB

  const int t   = threadIdx.x;
  const int w   = t >> 6, lane = t & 63;
  const int l31 = lane & 31, h = lane >> 5;
  const int wq  = w & 3, wk = w >> 2;
  const int bh  = blockIdx.x;
  const int b   = bh >> 4, hd = bh & (NH - 1);
  const int q0  = blockIdx.y * 128;

  const short* base  = qk + (size_t)(b * SEQ) * 2048 + hd * HD;
  const short* vbase = vt + ((size_t)(b * NH + hd) * HD) * SEQ;

  // Q B-frags in registers (pre-scaled): n=q, k=d=c*16+h*8+j
  s16x8 qf[4];
  {
    const short* qp = base + (size_t)(q0 + wq * 32 + l31) * 2048;
#pragma unroll
    for (int c = 0; c < 4; c++) qf[c] = *(const s16x8*)(qp + c * 16 + h * 8);
  }

  f32x16 o0 = {}, o1 = {};
  float lsum = 0.f;

  // role-split staging: waves 0-3 stage K, waves 4-7 stage V.
  // r7 conflict-free pattern over t&255: sr 0..63, sc in {0,16,32,48}.
  const int tt = t & 255;
  const int sr = tt >> 2, sc = (tt & 3) * 16;
  const bool stageK = (w < 4);

  s16x8 p0, p1;
  // load chunk 0
  {
    const short* gp = stageK ? (base + (size_t)sr * 2048 + CDIM + sc)
                             : (vbase + (size_t)sr * SEQ + sc);
    p0 = *(const s16x8*)gp; p1 = *(const s16x8*)(gp + 8);
  }
  // stage chunk 0 into buf0
  {
    short* dst = stageK ? smem : (smem + 64 * KPITCH);
    *(s16x8*)&dst[sr * KPITCH + sc]     = p0;
    *(s16x8*)&dst[sr * KPITCH + sc + 8] = p1;
  }
  __syncthreads();
  // load chunk 1
  {
    const short* gp = stageK ? (base + (size_t)(64 + sr) * 2048 + CDIM + sc)
                             : (vbase + (size_t)sr * SEQ + 64 + sc);
    p0 = *(const s16x8*)gp; p1 = *(const s16x8*)(gp + 8);
  }

  int cur = 0;
  for (int i = 0; i < SEQ / 64; i++) {
    short* Ksc = smem + cur * ABUFSZ;
    short* Vsc = Ksc + 64 * KPITCH;

    // stage chunk i+1 (in regs) into next buffer — overlaps compute below
    if (i <= SEQ / 64 - 2) {
      short* dst = (smem + (cur ^ 1) * ABUFSZ) + (stageK ? 0 : 64 * KPITCH);
      *(s16x8*)&dst[sr * KPITCH + sc]     = p0;
      *(s16x8*)&dst[sr * KPITCH + sc + 8] = p1;
    }

    // issue global loads for chunk i+2 (in flight across compute + barrier)
    if (i <= SEQ / 64 - 3) {
      int nn = (i + 2) * 64;
      const short* gp = stageK ? (base + (size_t)(nn + sr) * 2048 + CDIM + sc)
                               : (vbase + (size_t)sr * SEQ + nn + sc);
      p0 = *(const s16x8*)gp; p1 = *(const s16x8*)(gp + 8);
    }

    // ---- FROZEN per-wave compute (verbatim R5) ----
    const short* kbase = &Ksc[(wk * 32 + l31) * KPITCH + h * 8];
    s16x8 kf0 = *(const s16x8*)(kbase + 0);
    s16x8 kf1 = *(const s16x8*)(kbase + 16);
    s16x8 kf2 = *(const s16x8*)(kbase + 32);
    s16x8 kf3 = *(const s16x8*)(kbase + 48);
    s16x8 va0 = *(const s16x8*)&Vsc[l31 * KPITCH        + wk * 32 + h * 8];
    s16x8 va1 = *(const s16x8*)&Vsc[(32 + l31) * KPITCH + wk * 32 + h * 8];
    s16x8 vb0 = *(const s16x8*)&Vsc[l31 * KPITCH        + wk * 32 + 16 + h * 8];
    s16x8 vb1 = *(const s16x8*)&Vsc[(32 + l31) * KPITCH + wk * 32 + 16 + h * 8];

    // S^T[key][q]: A = K rows (wk half), B = Q regs. Two parallel chains.
    f32x16 sa = {}, sb = {};
    sa = __builtin_amdgcn_mfma_f32_32x32x16_bf16(kf0, qf[0], sa, 0, 0, 0);
    sb = __builtin_amdgcn_mfma_f32_32x32x16_bf16(kf2, qf[2], sb, 0, 0, 0);
    sa = __builtin_amdgcn_mfma_f32_32x32x16_bf16(kf1, qf[1], sa, 0, 0, 0);
    sb = __builtin_amdgcn_mfma_f32_32x32x16_bf16(kf3, qf[3], sb, 0, 0, 0);

    // softmax + pack: reg r -> key (r&3)+8*(r>>2)+4h (local to wave's half)
    uint2 pg[4];
#pragma unroll
    for (int g = 0; g < 4; g++) {
      float p0f = exp2_fast(sa[4 * g + 0] + sb[4 * g + 0]);
      float p1f = exp2_fast(sa[4 * g + 1] + sb[4 * g + 1]);
      float p2f = exp2_fast(sa[4 * g + 2] + sb[4 * g + 2]);
      float p3f = exp2_fast(sa[4 * g + 3] + sb[4 * g + 3]);
      lsum += (p0f + p1f) + (p2f + p3f);
      pg[g].x = f2bf2(p0f, p1f);
      pg[g].y = f2bf2(p2f, p3f);
    }

    // C->A via permlane32_swap (vdst=a=low-keys, vsrc=b=high-keys):
    //   new_a -> A-frag word0/1, new_b -> word2/3
    s16x8 pf[2];
#pragma unroll
    for (int kc2 = 0; kc2 < 2; kc2++) {
      unsigned a0 = pg[2 * kc2].x,     a1 = pg[2 * kc2].y;
      unsigned b0 = pg[2 * kc2 + 1].x, b1 = pg[2 * kc2 + 1].y;
      asm("v_permlane32_swap_b32 %0, %1" : "+v"(a0), "+v"(b0));
      asm("v_permlane32_swap_b32 %0, %1" : "+v"(a1), "+v"(b1));
      u32x4 f = {a0, a1, b0, b1};
      pf[kc2] = __builtin_bit_cast(s16x8, f);
    }

    // PV: O[q][d] += P * V over wave's 32 keys; B-frags preloaded above
    o0 = __builtin_amdgcn_mfma_f32_32x32x16_bf16(pf[0], va0, o0, 0, 0, 0);
    o1 = __builtin_amdgcn_mfma_f32_32x32x16_bf16(pf[0], va1, o1, 0, 0, 0);
    o0 = __builtin_amdgcn_mfma_f32_32x32x16_bf16(pf[1], vb0, o0, 0, 0, 0);
    o1 = __builtin_amdgcn_mfma_f32_32x32x16_bf16(pf[1], vb1, o1, 0, 0, 0);
    // ---- end FROZEN ----

    __syncthreads();                 // one barrier per chunk
    cur ^= 1;
  }

  // ---- epilogue: cross-wk reduction of O and l, normalize, store ----
  lsum += __shfl_xor(lsum, 32);          // combine h halves (disjoint keys)

  float* Ored = (float*)smem;            // [4 wq][32 q][64 d] = 32 KB
  float* Lred = (float*)smem + 8192;     // [128]

  if (wk == 0) {
#pragma unroll
    for (int r = 0; r < 16; r++) {
      int ql = (r & 3) + 8 * (r >> 2) + 4 * h;
      Ored[(wq * 32 + ql) * 64 + l31]      = o0[r];
      Ored[(wq * 32 + ql) * 64 + 32 + l31] = o1[r];
    }
    if (lane < 32) Lred[wq * 32 + l31] = lsum;
  }
  __syncthreads();
  if (wk == 1 && lane < 32) Lred[wq * 32 + l31] += lsum;
  __syncthreads();
  if (wk == 1) {
#pragma unroll
    for (int r = 0; r < 16; r++) {
      int ql = (r & 3) + 8 * (r >> 2) + 4 * h;
      float linv = 1.0f / Lred[wq * 32 + ql];
      int qg = q0 + wq * 32 + ql;
      size_t rowb = (size_t)(b * SEQ + qg) * CDIM + hd * HD;
      float v0 = (o0[r] + Ored[(wq * 32 + ql) * 64 + l31]) * linv;
      float v1 = (o1[r] + Ored[(wq * 32 + ql) * 64 + 32 + l31]) * linv;
      attn_out[rowb + l31]      = f2bf(v0);
      attn_out[rowb + 32 + l31] = f2bf(v1);
    }
  }
}

// ---------------------------------------------------------------------------
extern "C" void kernel_launch(void* const* d_in, const int* in_sizes, int n_in,
                              void* d_out, int out_size, void* d_ws, size_t ws_size,
                              hipStream_t stream)
{
  const float* x     = (const float*)d_in[0];
  const float* w_qkv = (const float*)d_in[1];
  const float* w_out = (const float*)d_in[2];
  const float* b_out = (const float*)d_in[3];

  short* qk_ws   = (short*)d_ws;                         // 4096*2048 = 16 MB
  short* vt_ws   = qk_ws  + (size_t)NTOK * 2048;         // 4096*1024 =  8 MB
  short* x_bf    = vt_ws  + (size_t)NTOK * CDIM;         // 4096*1024 =  8 MB
  short* attn_ws = x_bf;                                 // alias (x_bf dead)
  short* wqkv_bf = x_bf   + (size_t)NTOK * CDIM;         // 3072*1024 =  6 MB
  short* wout_bf = wqkv_bf + (size_t)3 * CDIM * CDIM;    // 1024*1024 =  2 MB

  dim3 blk(256);

  cvt_all<<<dim3(4096), blk, 0, stream>>>(x, w_qkv, w_out, x_bf, wqkv_bf, wout_bf);

  gemm128<0, 128><<<dim3(3 * CDIM / 128, NTOK / 128), blk, 0, stream>>>(
      x_bf, wqkv_bf, nullptr, qk_ws, vt_ws, NTOK, 3 * CDIM, CDIM);

  attn_kernel<<<dim3(BATCH * NH, SEQ / 128), dim3(512), 0, stream>>>(
      qk_ws, vt_ws, attn_ws);

  gemm128<1, 64><<<dim3(CDIM / 64, NTOK / 128), blk, 0, stream>>>(
      attn_ws, wout_bf, b_out, d_out, nullptr, NTOK, CDIM, CDIM);
}